// Round 17
// baseline (37.441 us; speedup 1.0000x reference)
//
#include <hip/hip_runtime.h>
#include <math.h>

#define W_ 128
#define H_ 96
#define C_ 128
#define HW_ (H_ * W_)          // 12288
#define K_ 81
#define FLOW_ELEMS (2 * 2 * H_ * W_)   // 49152
#define XPAD 144               // f1h padded cols: xp = x+4, zeros outside [4,131]
#define CP 64                  // channel pairs (u32 words per col)

typedef __fp16 f16x8 __attribute__((ext_vector_type(8)));
typedef float  f32x4 __attribute__((ext_vector_type(4)));

__device__ __forceinline__ unsigned pack_pair(float a, float b) {
    return __builtin_bit_cast(unsigned, __builtin_amdgcn_cvt_pkrtz(a, b));
}

// ---------------- repack f1: [b][c][y][x] f32 -> [b][y][xp][c] f16 ----------------
// (byte-identical to the R14 PASSING kernel)
__global__ __launch_bounds__(256) void repack_kernel(const float* __restrict__ f1,
                                                     unsigned* __restrict__ f1h32) {
    __shared__ unsigned lds[128 * 67];   // [x][cp], stride 67 (bank-spread)
    const int t = threadIdx.x;
    const int wid = t >> 6, lane = t & 63;
    const int L = (blockIdx.x & 7) * 24 + (blockIdx.x >> 3);   // 192 = 8*24
    const int y = L % H_;
    const int b = L / H_;
    const float* src = f1 + (size_t)b * C_ * HW_ + (size_t)y * W_;

    for (int it = 0; it < 16; ++it) {
        const int cp = it * 4 + wid;     // 0..63
        const float2 v0 = *(const float2*)(src + (size_t)(2 * cp) * HW_ + 2 * lane);
        const float2 v1 = *(const float2*)(src + (size_t)(2 * cp + 1) * HW_ + 2 * lane);
        lds[(2 * lane) * 67 + cp]     = pack_pair(v0.x, v1.x);
        lds[(2 * lane + 1) * 67 + cp] = pack_pair(v0.y, v1.y);
    }
    __syncthreads();

    unsigned* dst = f1h32 + (size_t)(b * H_ + y) * XPAD * CP;
    for (int it = 0; it < 32; ++it) {
        const int flat = it * 256 + t;
        const int x = flat >> 6, cp = flat & 63;
        dst[(size_t)(x + 4) * CP + cp] = lds[x * 67 + cp];
    }
    for (int i = t; i < 16 * CP; i += 256) {
        const int col = i >> 6, cp = i & 63;
        const int xp = (col < 4) ? col : 128 + col;
        dst[(size_t)xp * CP + cp] = 0u;
    }
}

// ---------------- fused MFMA corr + softmax + flow, barrier-free corr phase ----
// Block = 256 thr (4 waves) per (b, y0, xh) = 64 px; wave wid owns 16-px tile
// px0 = xh*64 + wid*16 and EXCLUSIVELY owns corr_lds rows [wid*16, wid*16+16).
// Per dy: B-frags for dy+1 load into named regs (8 x uint4, direct from the
// repacked f16 tensor -- no LDS staging) while MFMA + band extract run on dy.
// NO barriers until softmax. A-frag/B-addr/extract/softmax = R14-verified.
__global__ __launch_bounds__(256) void fused_kernel(const float* __restrict__ f0,
                                                    const __fp16* __restrict__ f1h,
                                                    float* __restrict__ out) {
    __shared__ float corr_lds[64][85];   // stride 85
    __shared__ float mbuf[64], ibuf[64];

    const int t = threadIdx.x;
    const int wid = t >> 6, l = t & 63;
    const int L = (blockIdx.x & 7) * 48 + (blockIdx.x >> 3);   // 384 = 8*48
    const int xh = L & 1;
    const int y0 = (L >> 1) % H_;
    const int b  = L / (2 * H_);
    const int px0 = xh * 64 + wid * 16;  // wave's absolute tile base

    // per-wave zero of OWN corr rows (no cross-wave interaction)
    {
        float* myrows = &corr_lds[wid * 16][0];
        for (int i = l; i < 16 * 85; i += 64) myrows[i] = 0.f;
    }

    // ---- A-frags straight from f32 f0 (R14-verified): row=l&15, k=(l>>4)*8+j ----
    f16x8 a[4];
    {
        const float* f0p = f0 + (size_t)b * C_ * HW_ + (size_t)y0 * W_ + px0 + (l & 15);
#pragma unroll
        for (int kk = 0; kk < 4; ++kk) {
            f16x8 av;
#pragma unroll
            for (int j = 0; j < 8; ++j)
                av[j] = (__fp16)f0p[(size_t)(kk * 32 + (l >> 4) * 8 + j) * HW_];
            a[kk] = av;
        }
    }

    // ---- pipeline helpers: named B-frag sets, direct global reads ----
    const int co = (l >> 4) * 8;
    auto LOADB = [&](int dy, uint4 (&bf)[8], bool& ok) {
        const int r = y0 + dy - 4;
        ok = (r >= 0) && (r < H_);
        const __fp16* bp = f1h + (size_t)(b * H_ + (ok ? r : 0)) * XPAD * C_;
#pragma unroll
        for (int kk = 0; kk < 4; ++kk) {
            bf[2 * kk]     = *(const uint4*)(bp + (size_t)(px0 + (l & 15)) * C_ + kk * 32 + co);
            bf[2 * kk + 1] = *(const uint4*)(bp + (size_t)(px0 + 16 + (l & 15)) * C_ + kk * 32 + co);
        }
    };
    auto COMPUTE = [&](int dy, const uint4 (&bf)[8]) {
        f32x4 accA = {0.f, 0.f, 0.f, 0.f}, accB = {0.f, 0.f, 0.f, 0.f};
#pragma unroll
        for (int kk = 0; kk < 4; ++kk) {
            accA = __builtin_amdgcn_mfma_f32_16x16x32_f16(
                a[kk], __builtin_bit_cast(f16x8, bf[2 * kk]), accA, 0, 0, 0);
            accB = __builtin_amdgcn_mfma_f32_16x16x32_f16(
                a[kk], __builtin_bit_cast(f16x8, bf[2 * kk + 1]), accB, 0, 0, 0);
        }
        // band extraction (R14-verified): C col=l&15 (j), row=(l>>4)*4+rg (i)
#pragma unroll
        for (int h = 0; h < 2; ++h) {
            const f32x4 acc = h ? accB : accA;
#pragma unroll
            for (int rg = 0; rg < 4; ++rg) {
                const int i2 = (l >> 4) * 4 + rg;
                const int j2 = h * 16 + (l & 15);
                const int dxw = j2 - i2;
                if (dxw >= 0 && dxw <= 8)
                    corr_lds[wid * 16 + i2][dy * 9 + dxw] = acc[rg];
            }
        }
    };

    uint4 bfA[8], bfB[8];
    bool okA, okB;

    LOADB(0, bfA, okA);
#pragma unroll
    for (int d2 = 0; d2 < 5; ++d2) {
        {   // even dy = 2*d2 (consumes A)
            const int dy = 2 * d2;
            if (dy + 1 < 9) LOADB(dy + 1, bfB, okB);   // in flight over MFMA
            if (okA) COMPUTE(dy, bfA);
        }
        if (2 * d2 + 1 < 9) {                          // odd dy (consumes B)
            const int dy = 2 * d2 + 1;
            if (dy + 1 < 9) LOADB(dy + 1, bfA, okA);
            if (okB) COMPUTE(dy, bfB);
        }
    }
    __syncthreads();                     // corr_lds complete (the ONLY corr barrier)

    const float scale = 0.08838834764831845f;     // 1/sqrt(128)

    // ---- pass 1: thread-per-px softmax + flow (R14-verified) ----
    if (t < 64) {
        float m = -1e30f;
#pragma unroll 9
        for (int k = 0; k < K_; ++k) m = fmaxf(m, corr_lds[t][k] * scale);
        float s = 0.f, fx = 0.f, fy = 0.f;
#pragma unroll 9
        for (int k = 0; k < K_; ++k) {
            const float e = __expf(corr_lds[t][k] * scale - m);
            s += e;
            fx += e * (float)(k % 9 - 4);
            fy += e * (float)(k / 9 - 4);
        }
        const float inv = 1.f / s;
        mbuf[t] = m;
        ibuf[t] = inv;
        const int x = xh * 64 + t;
        out[((size_t)(b * 2 + 0) * H_ + y0) * W_ + x] = fx * inv;
        out[((size_t)(b * 2 + 1) * H_ + y0) * W_ + x] = fy * inv;
    }
    __syncthreads();

    // ---- pass 2: coalesced match_prob writeout (R14-verified) ----
    float* mp = out + FLOW_ELEMS + ((size_t)b * HW_ + (size_t)y0 * W_ + xh * 64) * K_;
    for (int f = t; f < 64 * K_; f += 256) {
        const int px = f / K_;
        const int k = f - px * K_;
        mp[f] = __expf(corr_lds[px][k] * scale - mbuf[px]) * ibuf[px];
    }
}

extern "C" void kernel_launch(void* const* d_in, const int* in_sizes, int n_in,
                              void* d_out, int out_size, void* d_ws, size_t ws_size,
                              hipStream_t stream) {
    (void)in_sizes; (void)n_in; (void)out_size; (void)ws_size;
    const float* f0 = (const float*)d_in[0];
    const float* f1 = (const float*)d_in[1];
    float* out = (float*)d_out;
    unsigned* f1h32 = (unsigned*)d_ws;   // 2*96*144*64 u32 = 7.08 MB

    repack_kernel<<<192, 256, 0, stream>>>(f1, f1h32);
    fused_kernel<<<384, 256, 0, stream>>>(f0, (const __fp16*)d_ws, out);
}

// Round 18
// 27.476 us; speedup vs baseline: 1.3627x; 1.3627x over previous
//
#include <hip/hip_runtime.h>
#include <math.h>

#define W_ 128
#define H_ 96
#define C_ 128
#define HW_ (H_ * W_)          // 12288
#define K_ 81
#define FLOW_ELEMS (2 * 2 * H_ * W_)   // 49152
#define TCOLS 80               // staged xp cols per block (wave tiles need <= 79)
#define TSTR 66                // u32 stride per col (R16-verified layout)

typedef __fp16 f16x8 __attribute__((ext_vector_type(8)));
typedef float  f32x4 __attribute__((ext_vector_type(4)));

__device__ __forceinline__ unsigned pack_pair(float a, float b) {
    return __builtin_bit_cast(unsigned, __builtin_amdgcn_cvt_pkrtz(a, b));
}

// R16-verified fused kernel + round-18 changes:
//  (1) 2-deep load pipeline (3 named reg sets, static rotation, dy unrolled)
//  (2) float4 staging loads (same slot coverage / LDS layout as R16)
//  (3) softmax pass-1 parallelized across all 256 threads (k-strided partials)
// Block = 256 thr (4 waves) per (b, y0, xh) = 64 px. Grid = 384 (8 XCD x 48).
__global__ __launch_bounds__(256) void fused_kernel(const float* __restrict__ f0,
                                                    const float* __restrict__ f1,
                                                    float* __restrict__ out) {
    __shared__ unsigned tile[TCOLS * TSTR];   // [col][cp] (R16 layout)
    __shared__ float corr_lds[64][85];        // stride 85
    __shared__ float mbuf[64], ibuf[64];
    __shared__ float pmax[4][68], psum[4][68], pfxb[4][68], pfyb[4][68];

    const int t = threadIdx.x;
    const int wid = t >> 6, l = t & 63;
    const int L = (blockIdx.x & 7) * 48 + (blockIdx.x >> 3);   // 384 = 8*48
    const int xh = L & 1;
    const int y0 = (L >> 1) % H_;
    const int b  = L / (2 * H_);
    const int px0 = xh * 64 + wid * 16;       // wave's absolute pixel base

    // ---- per-slot staging constants: 5 slots/lane, slot = (cp, col-quad) ----
    // s = i*256+t: cp = s/20, q = s%20; quad covers sample x0..x0+3,
    // x0 = xh*64 + 4q - 4 (fully in iff 0 <= x0 <= 124); col_local = 4q+d.
    int g_off[5], lds_w[5];
    bool g_ok[5];
#pragma unroll
    for (int i = 0; i < 5; ++i) {
        const int s = i * 256 + t;
        const int cp = s / 20;
        const int q = s - cp * 20;
        const int x0 = xh * 64 + 4 * q - 4;
        g_ok[i] = (x0 >= 0) && (x0 <= 124);
        g_off[i] = 2 * cp * HW_ + (g_ok[i] ? x0 : 0);
        lds_w[i] = (4 * q) * TSTR + cp;
    }
    const float* f1base = f1 + (size_t)b * C_ * HW_;

    // ---- A-frags straight from f32 f0 (R14-verified): row=l&15, k=(l>>4)*8+j ----
    f16x8 a[4];
    {
        const float* f0p = f0 + (size_t)b * C_ * HW_ + (size_t)y0 * W_ + px0 + (l & 15);
#pragma unroll
        for (int kk = 0; kk < 4; ++kk) {
            f16x8 av;
#pragma unroll
            for (int j = 0; j < 8; ++j)
                av[j] = (__fp16)f0p[(size_t)(kk * 32 + (l >> 4) * 8 + j) * HW_];
            a[kk] = av;
        }
    }

    // ---- pipeline helpers (named reg sets; pure float4 loads, pack at write) ----
    auto LOADDY = [&](int dy, float4 (&va)[5], float4 (&vb)[5], bool& ok) {
        const int r = y0 + dy - 4;
        ok = (r >= 0) && (r < H_);
        const float* f1b = f1base + (size_t)(ok ? r : 0) * W_;
#pragma unroll
        for (int i = 0; i < 5; ++i) {
            float4 x = {0.f, 0.f, 0.f, 0.f}, y = {0.f, 0.f, 0.f, 0.f};
            if (ok && g_ok[i]) {
                x = *(const float4*)(f1b + g_off[i]);
                y = *(const float4*)(f1b + g_off[i] + HW_);
            }
            va[i] = x; vb[i] = y;
        }
    };
    auto WRITEDY = [&](const float4 (&va)[5], const float4 (&vb)[5]) {
#pragma unroll
        for (int i = 0; i < 5; ++i) {
            tile[lds_w[i]]            = pack_pair(va[i].x, vb[i].x);
            tile[lds_w[i] + TSTR]     = pack_pair(va[i].y, vb[i].y);
            tile[lds_w[i] + 2 * TSTR] = pack_pair(va[i].z, vb[i].z);
            tile[lds_w[i] + 3 * TSTR] = pack_pair(va[i].w, vb[i].w);
        }
    };
    auto COMPUTE = [&](int dy) {       // byte-identical to R16
        f32x4 accA = {0.f, 0.f, 0.f, 0.f}, accB = {0.f, 0.f, 0.f, 0.f};
#pragma unroll
        for (int kk = 0; kk < 4; ++kk) {
            const int off = kk * 16 + (l >> 4) * 4;
            {
                const int col = wid * 16 + (l & 15);
                const uint2 lo = *(const uint2*)&tile[col * TSTR + off];
                const uint2 hi = *(const uint2*)&tile[col * TSTR + off + 2];
                const uint4 u = {lo.x, lo.y, hi.x, hi.y};
                accA = __builtin_amdgcn_mfma_f32_16x16x32_f16(
                    a[kk], __builtin_bit_cast(f16x8, u), accA, 0, 0, 0);
            }
            {
                const int col = wid * 16 + 16 + (l & 15);
                const uint2 lo = *(const uint2*)&tile[col * TSTR + off];
                const uint2 hi = *(const uint2*)&tile[col * TSTR + off + 2];
                const uint4 u = {lo.x, lo.y, hi.x, hi.y};
                accB = __builtin_amdgcn_mfma_f32_16x16x32_f16(
                    a[kk], __builtin_bit_cast(f16x8, u), accB, 0, 0, 0);
            }
        }
#pragma unroll
        for (int h = 0; h < 2; ++h) {
            const f32x4 acc = h ? accB : accA;
#pragma unroll
            for (int rg = 0; rg < 4; ++rg) {
                const int i2 = (l >> 4) * 4 + rg;
                const int j2 = h * 16 + (l & 15);
                const int dxw = j2 - i2;
                if (dxw >= 0 && dxw <= 8)
                    corr_lds[wid * 16 + i2][dy * 9 + dxw] = acc[rg];
            }
        }
    };

    float4 vaA[5], vbA[5], vaB[5], vbB[5], vaC[5], vbC[5];
    bool okA, okB, okC;

    // issue two dy rows of loads before any dependent work
    LOADDY(0, vaA, vbA, okA);
    LOADDY(1, vaB, vbB, okB);
    for (int i = t; i < 64 * 85; i += 256) (&corr_lds[0][0])[i] = 0.f;
    __syncthreads();                      // corr_lds zero visible

    // ---- fully-unrolled dy loop, 3-set static rotation (2-deep pipeline) ----
    // dy: write set W(dy%3: A,B,C,A,B,C,A,B,C), load dy+2 into set (dy+2)%3
    if (okA) WRITEDY(vaA, vbA); __syncthreads();
    LOADDY(2, vaC, vbC, okC);
    if (okA) COMPUTE(0); __syncthreads();

    if (okB) WRITEDY(vaB, vbB); __syncthreads();
    LOADDY(3, vaA, vbA, okA);
    if (okB) COMPUTE(1); __syncthreads();

    if (okC) WRITEDY(vaC, vbC); __syncthreads();
    LOADDY(4, vaB, vbB, okB);
    if (okC) COMPUTE(2); __syncthreads();

    if (okA) WRITEDY(vaA, vbA); __syncthreads();
    LOADDY(5, vaC, vbC, okC);
    if (okA) COMPUTE(3); __syncthreads();

    if (okB) WRITEDY(vaB, vbB); __syncthreads();
    LOADDY(6, vaA, vbA, okA);
    if (okB) COMPUTE(4); __syncthreads();

    if (okC) WRITEDY(vaC, vbC); __syncthreads();
    LOADDY(7, vaB, vbB, okB);
    if (okC) COMPUTE(5); __syncthreads();

    if (okA) WRITEDY(vaA, vbA); __syncthreads();
    LOADDY(8, vaC, vbC, okC);
    if (okA) COMPUTE(6); __syncthreads();

    if (okB) WRITEDY(vaB, vbB); __syncthreads();
    if (okB) COMPUTE(7); __syncthreads();

    if (okC) WRITEDY(vaC, vbC); __syncthreads();
    if (okC) COMPUTE(8); __syncthreads();

    const float scale = 0.08838834764831845f;     // 1/sqrt(128)

    // ---- pass 1 (parallelized): px = t&63, part = t>>6 handles k = part+4j ----
    {
        const int px = t & 63;
        const int part = t >> 6;
        float pm = -1e30f;
        for (int k = part; k < K_; k += 4)
            pm = fmaxf(pm, corr_lds[px][k] * scale);
        pmax[part][px] = pm;
        __syncthreads();
        const float m = fmaxf(fmaxf(pmax[0][px], pmax[1][px]),
                              fmaxf(pmax[2][px], pmax[3][px]));
        float ps = 0.f, pfx = 0.f, pfy = 0.f;
        for (int k = part; k < K_; k += 4) {
            const float e = __expf(corr_lds[px][k] * scale - m);
            ps += e;
            pfx += e * (float)(k % 9 - 4);
            pfy += e * (float)(k / 9 - 4);
        }
        psum[part][px] = ps; pfxb[part][px] = pfx; pfyb[part][px] = pfy;
        __syncthreads();
        if (t < 64) {
            const float s = psum[0][t] + psum[1][t] + psum[2][t] + psum[3][t];
            const float inv = 1.f / s;
            mbuf[t] = m;          // m identical across parts for same px
            ibuf[t] = inv;
            const float fx = pfxb[0][t] + pfxb[1][t] + pfxb[2][t] + pfxb[3][t];
            const float fy = pfyb[0][t] + pfyb[1][t] + pfyb[2][t] + pfyb[3][t];
            const int x = xh * 64 + t;
            out[((size_t)(b * 2 + 0) * H_ + y0) * W_ + x] = fx * inv;
            out[((size_t)(b * 2 + 1) * H_ + y0) * W_ + x] = fy * inv;
        }
    }
    __syncthreads();

    // ---- pass 2: coalesced match_prob writeout (R14-verified) ----
    float* mp = out + FLOW_ELEMS + ((size_t)b * HW_ + (size_t)y0 * W_ + xh * 64) * K_;
    for (int f = t; f < 64 * K_; f += 256) {
        const int px = f / K_;
        const int k = f - px * K_;
        mp[f] = __expf(corr_lds[px][k] * scale - mbuf[px]) * ibuf[px];
    }
}

extern "C" void kernel_launch(void* const* d_in, const int* in_sizes, int n_in,
                              void* d_out, int out_size, void* d_ws, size_t ws_size,
                              hipStream_t stream) {
    (void)in_sizes; (void)n_in; (void)out_size; (void)d_ws; (void)ws_size;
    const float* f0 = (const float*)d_in[0];
    const float* f1 = (const float*)d_in[1];
    float* out = (float*)d_out;

    fused_kernel<<<384, 256, 0, stream>>>(f0, f1, out);
}